// Round 11
// baseline (29.087 us; speedup 1.0000x reference)
//
#include <hip/hip_runtime.h>

// Capsule agreement routing, fp32.
// preds [8,32,14,14,32,16], b [1,32,14,14,32], out v [8,32,14,14,16].
//
// 16 sites per 64-lane wave; lane (s_w = lane>>2, q = lane&3) owns rows
// i = q + 4k (k=0..7) x all 16 d of site s_w (p[8][4] = 128 VGPRs).
//
// GAP-FREE staging: global_load_lds (OFF=0), EIGHT 4-KB phases (phase ph =
// rows [4ph,4ph+4) of all 16 sites) through FOUR 4-KB LDS slots
// (16 KB/wave, 64 KB/block). All 4 slots issued up front; each phase:
// counted vmcnt -> 4 ds_read_b128 -> fused pass-0 FMA -> lgkm0 -> reissue.
// Outstanding DMA stays 12-16 KB/wave for the whole staging period
// (monotone vmcnt 16,12,12,12,12,12,8,4,0 -- full drain only at the end).
// Pass-0 softmax (exp2/sum/rcp) depends only on b: computed while DMAs fly;
// per-phase s~ accumulation absorbs pass-0's FMA work into the pipeline.
//
// Stride-4 ownership => a 4-row phase gives EVERY lane exactly 1 row
// (phase-local row j = q): full-wave unmasked b128 reads.
// XOR swizzle both-sides (LDS dest linear, source pre-swizzled):
//   site x, phase-local f4 m (=4j+u) stored at slot x*16 + (m ^ (x&7));
//   DMA src f4 = x*128 + 16*ph + (m ^ (x&7)).
//   Verified end-to-end: (ph=1,x=5,row7,u=2): slot pos 91 <- src f4 670 =
//   direct index. Read bank-group (4(q&1)+u)^(s_w&7): exactly 8 lanes/group.
// __launch_bounds__(256,2): ~180 VGPR, no spill (R7's lesson).
//
// Math (all cross-lane = quad_perm DPP, zero LDS-pipe ops):
//   b in log2 domain -> e = exp2(bl); softmax sum 7 adds + 2 DPP; r=rcp
//   s~_d = sum_i e_i p_id (fused per phase); squash: sq = r^2|s~|^2,
//   f = sq/(1+sq)/sqrt(sq+eps)*r; agreement: bl += (f*log2e)*dot(p,s~).

#define EPSQ 1e-7f
#define LOG2E 1.442695041f

constexpr int OHW   = 6272;           // 32*14*14
constexpr int SITES = 50176;          // 8 * OHW
constexpr int THREADS = 256;
constexpr int BLOCKS  = SITES / 64;   // 784 (16 sites/wave * 4 waves/block)

__device__ __forceinline__ float dpp1(float x) {   // quad_perm xor 1
    return __int_as_float(__builtin_amdgcn_mov_dpp(__float_as_int(x), 0xB1, 0xF, 0xF, true));
}
__device__ __forceinline__ float dpp2(float x) {   // quad_perm xor 2
    return __int_as_float(__builtin_amdgcn_mov_dpp(__float_as_int(x), 0x4E, 0xF, 0xF, true));
}
__device__ __forceinline__ void fma4(float4& a, float c, const float4& x) {
    a.x = fmaf(c, x.x, a.x); a.y = fmaf(c, x.y, a.y);
    a.z = fmaf(c, x.z, a.z); a.w = fmaf(c, x.w, a.w);
}
__device__ __forceinline__ float dot4(const float4& a, const float4& b) {
    return fmaf(a.x, b.x, fmaf(a.y, b.y, fmaf(a.z, b.z, a.w * b.w)));
}
__device__ __forceinline__ void qred4(float4& a) {
    a.x += dpp1(a.x); a.y += dpp1(a.y); a.z += dpp1(a.z); a.w += dpp1(a.w);
    a.x += dpp2(a.x); a.y += dpp2(a.y); a.z += dpp2(a.z); a.w += dpp2(a.w);
}

__device__ __forceinline__ void gload16(const char* g, float4* l) {
    __builtin_amdgcn_global_load_lds(
        (const __attribute__((address_space(1))) void*)g,
        (__attribute__((address_space(3))) void*)l, 16, 0, 0);
}

__global__ __launch_bounds__(256, 2) void routing_kernel(
    const float* __restrict__ preds,
    const float* __restrict__ bparam,
    float* __restrict__ out)
{
    __shared__ float4 lds4[4096];     // 64 KB = 4 waves x 1024 f4 (4 slots x 256)
    const int tid  = threadIdx.x;
    const int lane = tid & 63;
    const int wib  = tid >> 6;
    const int wave = blockIdx.x * 4 + wib;
    const int q    = lane & 3;        // row class: rows q, q+4, ..., q+28
    const int s_w  = lane >> 2;       // within-wave site 0..15
    const int site = wave * 16 + s_w;

    float4* wlds = lds4 + wib * 1024;
    const char* pgc = (const char*)((const float4*)preds + (size_t)wave * 2048);

    // ---- routing logits FIRST (oldest 8 entries in the vmcnt queue)
    const int sohw = site % OHW;
    const float* bs = bparam + (size_t)sohw * 32 + q;
    float bl[8];
    #pragma unroll
    for (int k = 0; k < 8; ++k) bl[k] = bs[4 * k];
    asm volatile("" ::: "memory");    // pin b-loads ahead of the DMA queue

    // ---- per-lane DMA source offsets (bytes) for one phase's 4 instrs:
    // instr t covers slot positions [t*64, t*64+64); pos = t*64+lane;
    // x = pos>>4 = 4t + (lane>>4); m = lane&15;
    // src f4 = x*128 + 16*ph + (m ^ (x&7))   (ph added at issue, runtime)
    const int hi  = lane >> 4;
    const int m4  = lane & 15;
    int vofs[4];
    #pragma unroll
    for (int t = 0; t < 4; ++t) {
        const int x = 4 * t + hi;
        vofs[t] = (x * 128 + (m4 ^ (x & 7))) * 16;
    }

    // ---- prologue: issue phases 0..3 into slots 0..3 (16 KB in flight)
    #pragma unroll
    for (int ph = 0; ph < 4; ++ph)
        #pragma unroll
        for (int t = 0; t < 4; ++t)
            gload16(pgc + vofs[t] + ph * 256, wlds + ph * 256 + t * 64);

    // ---- pass-0 softmax from b alone, while DMAs are in flight
    asm volatile("s_waitcnt vmcnt(16)" ::: "memory");   // b landed
    float el[8];
    float sm = 0.0f;
    #pragma unroll
    for (int k = 0; k < 8; ++k) {
        bl[k] *= LOG2E;                                 // log2 domain
        el[k] = __builtin_amdgcn_exp2f(bl[k]);
        sm += el[k];
    }
    sm += dpp1(sm);
    sm += dpp2(sm);
    const float r0 = __frcp_rn(sm);

    float4 p[8][4];                   // p[k][u] = row q+4k, comps 4u..4u+3
    float4 s0 = {0,0,0,0}, s1 = {0,0,0,0}, s2 = {0,0,0,0}, s3 = {0,0,0,0};
    const int rbase = s_w * 16;
    const int rkey  = s_w & 7;

    // phase k: read this lane's row (phase-local row j = q) + fused pass-0 FMA
    auto read_fuse = [&](int k) {
        const float4* buf = wlds + (k & 3) * 256;
        #pragma unroll
        for (int u = 0; u < 4; ++u)
            p[k][u] = buf[rbase + ((4 * q + u) ^ rkey)];
        fma4(s0, el[k], p[k][0]); fma4(s1, el[k], p[k][1]);
        fma4(s2, el[k], p[k][2]); fma4(s3, el[k], p[k][3]);
    };

    // ---- gap-free pipeline: vmcnt stays >=12 until the tail
    asm volatile("s_waitcnt vmcnt(12)" ::: "memory");   // ph0
    read_fuse(0);
    asm volatile("s_waitcnt lgkmcnt(0)" ::: "memory");
    #pragma unroll
    for (int t = 0; t < 4; ++t) gload16(pgc + vofs[t] + 4 * 256, wlds + 0 * 256 + t * 64);

    asm volatile("s_waitcnt vmcnt(12)" ::: "memory");   // ph1
    read_fuse(1);
    asm volatile("s_waitcnt lgkmcnt(0)" ::: "memory");
    #pragma unroll
    for (int t = 0; t < 4; ++t) gload16(pgc + vofs[t] + 5 * 256, wlds + 1 * 256 + t * 64);

    asm volatile("s_waitcnt vmcnt(12)" ::: "memory");   // ph2
    read_fuse(2);
    asm volatile("s_waitcnt lgkmcnt(0)" ::: "memory");
    #pragma unroll
    for (int t = 0; t < 4; ++t) gload16(pgc + vofs[t] + 6 * 256, wlds + 2 * 256 + t * 64);

    asm volatile("s_waitcnt vmcnt(12)" ::: "memory");   // ph3
    read_fuse(3);
    asm volatile("s_waitcnt lgkmcnt(0)" ::: "memory");
    #pragma unroll
    for (int t = 0; t < 4; ++t) gload16(pgc + vofs[t] + 7 * 256, wlds + 3 * 256 + t * 64);

    asm volatile("s_waitcnt vmcnt(12)" ::: "memory");   // ph4
    read_fuse(4);
    asm volatile("s_waitcnt vmcnt(8)"  ::: "memory");   // ph5
    read_fuse(5);
    asm volatile("s_waitcnt vmcnt(4)"  ::: "memory");   // ph6
    read_fuse(6);
    asm volatile("s_waitcnt vmcnt(0)"  ::: "memory");   // ph7
    read_fuse(7);

    // ---- finish pass 0: reduce + squash
    float f;
    {
        qred4(s0); qred4(s1); qred4(s2); qred4(s3);
        const float sqt = dot4(s0, s0) + dot4(s1, s1) + dot4(s2, s2) + dot4(s3, s3);
        const float sq  = r0 * r0 * sqt;
        f = sq * __frcp_rn(1.0f + sq) * __frsqrt_rn(sq + EPSQ) * r0;
    }

    // ---- routing iterations 1..3 (full passes)
    #pragma unroll
    for (int it = 0; it < 3; ++it) {
        const float fl = f * LOG2E;
        #pragma unroll
        for (int k = 0; k < 8; ++k) {
            const float qk = dot4(p[k][0], s0) + dot4(p[k][1], s1)
                           + dot4(p[k][2], s2) + dot4(p[k][3], s3);
            bl[k] = fmaf(fl, qk, bl[k]);
        }
        float smx = 0.0f;
        float4 t0 = {0,0,0,0}, t1 = {0,0,0,0}, t2 = {0,0,0,0}, t3 = {0,0,0,0};
        #pragma unroll
        for (int k = 0; k < 8; ++k) {
            const float e = __builtin_amdgcn_exp2f(bl[k]);
            smx += e;
            fma4(t0, e, p[k][0]); fma4(t1, e, p[k][1]);
            fma4(t2, e, p[k][2]); fma4(t3, e, p[k][3]);
        }
        smx += dpp1(smx);
        smx += dpp2(smx);
        const float r = __frcp_rn(smx);
        qred4(t0); qred4(t1); qred4(t2); qred4(t3);
        s0 = t0; s1 = t1; s2 = t2; s3 = t3;

        const float sqt = dot4(s0, s0) + dot4(s1, s1) + dot4(s2, s2) + dot4(s3, s3);
        const float sq  = r * r * sqt;
        f = sq * __frcp_rn(1.0f + sq) * __frsqrt_rn(sq + EPSQ) * r;
    }

    // epilogue: all 64 lanes store one float4 -> contiguous 1 KB per wave
    float4 wv = (q == 0) ? s0 : (q == 1) ? s1 : (q == 2) ? s2 : s3;
    wv.x *= f; wv.y *= f; wv.z *= f; wv.w *= f;
    ((float4*)out)[(size_t)wave * 64 + lane] = wv;
}

extern "C" void kernel_launch(void* const* d_in, const int* in_sizes, int n_in,
                              void* d_out, int out_size, void* d_ws, size_t ws_size,
                              hipStream_t stream) {
    const float* preds  = (const float*)d_in[0];
    const float* bparam = (const float*)d_in[1];
    float* out = (float*)d_out;
    routing_kernel<<<BLOCKS, THREADS, 0, stream>>>(preds, bparam, out);
}

// Round 12
// 28.495 us; speedup vs baseline: 1.0208x; 1.0208x over previous
//
#include <hip/hip_runtime.h>

// Capsule agreement routing, fp32.
// preds [8,32,14,14,32,16], b [1,32,14,14,32], out v [8,32,14,14,16].
//
// CROSS-CHUNK SOFTWARE PIPELINE: each 64-lane wave owns 16 sites as TWO
// 8-site chunks (A,B). Chunk B's staging overlaps chunk A's entire compute,
// keeping the wave memory-active ~75% of its life (the R4..R11 plateau is
// consistent with CU-level memory duty cycle ~50% x 10 B/cyc/CU).
//
// Per chunk (R10's verified mapping): lane (s_w = lane>>3, g = lane&7) owns
// rows i = g+8k (k=0..3) x all 16 d of site s_w -> p[4][4] = 64 VGPR.
// Staging: global_load_lds (OFF=0), 4 phases x 4 KB (rows [8ph,8ph+8) of
// all 8 sites) through a 2-slot ring (8 KB/wave, 32 KB/block), counted
// vmcnt(4) per cluster, vmcnt(0) only at the very end.
// XOR swizzle both-sides (verified R10, absmax 2e-3):
//   site x, phase-local f4 m stored at slot x*32 + (m ^ x);
//   DMA src f4 = x*128 + 32*ph + (m ^ x); read slot s_w*32 + ((4g+u)^s_w)
//   -> exactly 8 lanes per bank-group on read, linear DMA write.
//
// Schedule (vmcnt bookkeeping in comments; b-loads drained early by their
// log2-conversion before the first counted wait):
//   issue Aph0,Aph1                         | 8 DMA out
//   c1: vm(4) rd A0; lgkm; issue Aph2       | 8
//   c2: vm(4) rd A1; lgkm; issue Aph3       | 8
//   c3: vm(4) rd A2; lgkm; issue Bph0       | 8
//   c4: vm(4) rd A3; lgkm; issue Bph1       | 8
//   A-pass0, agree
//   c5: vm(4) rd B0; lgkm; issue Bph2       | 8
//   A-pass1, agree
//   c6: vm(4) rd B1; lgkm; issue Bph3       | 8
//   A-pass2, agree
//   c7: vm(4) rd B2                         | 4
//   A-pass3, write A
//   c8: vm(0) rd B3                         | 0
//   B-pass0 + 3 iterations, write B
// sched_barrier(0) pins each cluster so the compiler can't collapse the
// interleave. __launch_bounds__(256,2): ~180 VGPR, no spill (R7 lesson).
//
// Math per pass (cross-lane = quad_perm + row_half_mirror DPP, zero
// LDS-pipe ops): b in log2 domain -> e = exp2(bl); softmax sum 3 adds +
// 3 DPP; r = rcp folded into squash: sq = r^2|s~|^2,
// f = sq/(1+sq)/sqrt(sq+eps)*r; agreement bl += (f*log2e)*dot(p,s~).

#define EPSQ 1e-7f
#define LOG2E 1.442695041f

constexpr int OHW   = 6272;           // 32*14*14
constexpr int SITES = 50176;          // 8 * OHW
constexpr int THREADS = 256;
constexpr int BLOCKS  = SITES / 64;   // 784 (16 sites/wave = 2 chunks of 8)

__device__ __forceinline__ float dpp1(float x) {   // quad_perm xor 1
    return __int_as_float(__builtin_amdgcn_mov_dpp(__float_as_int(x), 0xB1, 0xF, 0xF, true));
}
__device__ __forceinline__ float dpp2(float x) {   // quad_perm xor 2
    return __int_as_float(__builtin_amdgcn_mov_dpp(__float_as_int(x), 0x4E, 0xF, 0xF, true));
}
__device__ __forceinline__ float dpp4(float x) {   // row_half_mirror: l -> l^7 in each 8
    return __int_as_float(__builtin_amdgcn_mov_dpp(__float_as_int(x), 0x141, 0xF, 0xF, true));
}
__device__ __forceinline__ void fma4(float4& a, float c, const float4& x) {
    a.x = fmaf(c, x.x, a.x); a.y = fmaf(c, x.y, a.y);
    a.z = fmaf(c, x.z, a.z); a.w = fmaf(c, x.w, a.w);
}
__device__ __forceinline__ float dot4(const float4& a, const float4& b) {
    return fmaf(a.x, b.x, fmaf(a.y, b.y, fmaf(a.z, b.z, a.w * b.w)));
}
__device__ __forceinline__ void red8_4(float4& a) {
    a.x += dpp1(a.x); a.y += dpp1(a.y); a.z += dpp1(a.z); a.w += dpp1(a.w);
    a.x += dpp2(a.x); a.y += dpp2(a.y); a.z += dpp2(a.z); a.w += dpp2(a.w);
    a.x += dpp4(a.x); a.y += dpp4(a.y); a.z += dpp4(a.z); a.w += dpp4(a.w);
}

__device__ __forceinline__ void gload16(const char* g, float4* l) {
    __builtin_amdgcn_global_load_lds(
        (const __attribute__((address_space(1))) void*)g,
        (__attribute__((address_space(3))) void*)l, 16, 0, 0);
}

#define VMCNT4 asm volatile("s_waitcnt vmcnt(4)" ::: "memory")
#define VMCNT0 asm volatile("s_waitcnt vmcnt(0)" ::: "memory")
#define LGKM0  asm volatile("s_waitcnt lgkmcnt(0)" ::: "memory")
#define SBAR   __builtin_amdgcn_sched_barrier(0)

__global__ __launch_bounds__(256, 2) void routing_kernel(
    const float* __restrict__ preds,
    const float* __restrict__ bparam,
    float* __restrict__ out)
{
    __shared__ float4 lds4[2048];     // 32 KB = 4 waves x 2 slots x 256 f4
    const int tid  = threadIdx.x;
    const int lane = tid & 63;
    const int wib  = tid >> 6;
    const int wave = blockIdx.x * 4 + wib;
    const int g    = lane & 7;        // row class: rows g, g+8, g+16, g+24
    const int s_w  = lane >> 3;       // site-in-chunk 0..7
    const int siteA = wave * 16 + s_w;
    const int siteB = siteA + 8;

    float4* slot0 = lds4 + wib * 512;
    float4* slot1 = slot0 + 256;
    const char* pgA = (const char*)((const float4*)preds + (size_t)wave * 2048);
    const char* pgB = pgA + 16384;    // chunk B = next 8 sites (1024 f4)

    // ---- routing logits for both chunks (issued before the DMA queue)
    const float* bsA = bparam + (size_t)(siteA % OHW) * 32 + g;
    const float* bsB = bparam + (size_t)(siteB % OHW) * 32 + g;
    float blA[4], blB[4];
    #pragma unroll
    for (int k = 0; k < 4; ++k) { blA[k] = bsA[8 * k]; blB[k] = bsB[8 * k]; }

    // per-lane DMA source offsets (bytes) for one phase's 4 instrs:
    // instr t covers slot positions [t*64,+64); pos = t*64+lane;
    // x = 2t + (lane>>5); m = lane&31; src f4 = x*128 + 32*ph + (m ^ x)
    const int hi  = lane >> 5;
    const int w32 = lane & 31;
    int vofs[4];
    #pragma unroll
    for (int t = 0; t < 4; ++t) {
        const int x = 2 * t + hi;
        vofs[t] = (x * 128 + (w32 ^ x)) * 16;
    }

    // ---- prologue: A-ph0 -> slot0, A-ph1 -> slot1
    #pragma unroll
    for (int t = 0; t < 4; ++t) gload16(pgA + vofs[t], slot0 + t * 64);
    #pragma unroll
    for (int t = 0; t < 4; ++t) gload16(pgA + vofs[t] + 512, slot1 + t * 64);

    // consume b now (compiler inserts its own wait; drains b before c1)
    #pragma unroll
    for (int k = 0; k < 4; ++k) { blA[k] *= LOG2E; blB[k] *= LOG2E; }

    float4 pA[4][4], pB[4][4];        // [row k][comp u]: row g+8k, d 4u..4u+3
    const int rbase = s_w * 32;

    auto read_ph = [&](float4 (&p)[4][4], int k, const float4* buf) {
        #pragma unroll
        for (int u = 0; u < 4; ++u)
            p[k][u] = buf[rbase + ((4 * g + u) ^ s_w)];
    };

    // ---- staging clusters c1..c4 (A in regs; B-ph0/ph1 in flight at exit)
    VMCNT4; read_ph(pA, 0, slot0); LGKM0;
    #pragma unroll
    for (int t = 0; t < 4; ++t) gload16(pgA + vofs[t] + 1024, slot0 + t * 64); // Aph2
    SBAR;
    VMCNT4; read_ph(pA, 1, slot1); LGKM0;
    #pragma unroll
    for (int t = 0; t < 4; ++t) gload16(pgA + vofs[t] + 1536, slot1 + t * 64); // Aph3
    SBAR;
    VMCNT4; read_ph(pA, 2, slot0); LGKM0;
    #pragma unroll
    for (int t = 0; t < 4; ++t) gload16(pgB + vofs[t], slot0 + t * 64);        // Bph0
    SBAR;
    VMCNT4; read_ph(pA, 3, slot1); LGKM0;
    #pragma unroll
    for (int t = 0; t < 4; ++t) gload16(pgB + vofs[t] + 512, slot1 + t * 64);  // Bph1
    SBAR;

    float4 s0, s1, s2, s3;            // unnormalized s~, replicated across site
    float  f;                         // v = f * s~

    auto pass = [&](float4 (&p)[4][4], float (&bl)[4]) {
        float sm = 0.0f;
        s0 = make_float4(0,0,0,0); s1 = make_float4(0,0,0,0);
        s2 = make_float4(0,0,0,0); s3 = make_float4(0,0,0,0);
        #pragma unroll
        for (int k = 0; k < 4; ++k) {
            const float e = __builtin_amdgcn_exp2f(bl[k]);
            sm += e;
            fma4(s0, e, p[k][0]); fma4(s1, e, p[k][1]);
            fma4(s2, e, p[k][2]); fma4(s3, e, p[k][3]);
        }
        sm += dpp1(sm); sm += dpp2(sm); sm += dpp4(sm);
        const float r = __frcp_rn(sm);
        red8_4(s0); red8_4(s1); red8_4(s2); red8_4(s3);
        const float sqt = dot4(s0, s0) + dot4(s1, s1) + dot4(s2, s2) + dot4(s3, s3);
        const float sq  = r * r * sqt;
        f = sq * __frcp_rn(1.0f + sq) * __frsqrt_rn(sq + EPSQ) * r;
    };
    auto agree = [&](float4 (&p)[4][4], float (&bl)[4]) {
        const float fl = f * LOG2E;
        #pragma unroll
        for (int k = 0; k < 4; ++k) {
            const float qk = dot4(p[k][0], s0) + dot4(p[k][1], s1)
                           + dot4(p[k][2], s2) + dot4(p[k][3], s3);
            bl[k] = fmaf(fl, qk, bl[k]);
        }
    };

    // ---- A compute interleaved with B staging
    pass(pA, blA);                     // A pass0
    agree(pA, blA);
    VMCNT4; read_ph(pB, 0, slot0); LGKM0;
    #pragma unroll
    for (int t = 0; t < 4; ++t) gload16(pgB + vofs[t] + 1024, slot0 + t * 64); // Bph2
    SBAR;
    pass(pA, blA);                     // A pass1
    agree(pA, blA);
    VMCNT4; read_ph(pB, 1, slot1); LGKM0;
    #pragma unroll
    for (int t = 0; t < 4; ++t) gload16(pgB + vofs[t] + 1536, slot1 + t * 64); // Bph3
    SBAR;
    pass(pA, blA);                     // A pass2
    agree(pA, blA);
    VMCNT4; read_ph(pB, 2, slot0);
    SBAR;
    pass(pA, blA);                     // A pass3 (final)

    // write A: s~ replicated across the site's 8 lanes; lanes g<4 write
    if (g < 4) {
        float4 wv = (g == 0) ? s0 : (g == 1) ? s1 : (g == 2) ? s2 : s3;
        wv.x *= f; wv.y *= f; wv.z *= f; wv.w *= f;
        ((float4*)out)[(size_t)siteA * 4 + g] = wv;
    }

    VMCNT0; read_ph(pB, 3, slot1);
    SBAR;

    // ---- B compute (other waves/blocks are staging meanwhile)
    pass(pB, blB);                     // B pass0
    #pragma unroll
    for (int it = 0; it < 3; ++it) {
        agree(pB, blB);
        pass(pB, blB);
    }

    if (g < 4) {
        float4 wv = (g == 0) ? s0 : (g == 1) ? s1 : (g == 2) ? s2 : s3;
        wv.x *= f; wv.y *= f; wv.z *= f; wv.w *= f;
        ((float4*)out)[(size_t)siteB * 4 + g] = wv;
    }
}

extern "C" void kernel_launch(void* const* d_in, const int* in_sizes, int n_in,
                              void* d_out, int out_size, void* d_ws, size_t ws_size,
                              hipStream_t stream) {
    const float* preds  = (const float*)d_in[0];
    const float* bparam = (const float*)d_in[1];
    float* out = (float*)d_out;
    routing_kernel<<<BLOCKS, THREADS, 0, stream>>>(preds, bparam, out);
}